// Round 5
// baseline (175.924 us; speedup 1.0000x reference)
//
#include <hip/hip_runtime.h>
#include <hip/hip_bf16.h>

// CARAFE pipeline, 4 kernels, small-LDS / multi-block-per-CU.
// x: (4, 256, 64, 64) fp32
// w_down: (128, 256) ; b_down: (128)
// w_enc: (100, 128, 3, 3) ; b_enc: (100)
// w_out: (256, 256) ; b_out: (256)
// out z: (4, 256, 128, 128) fp32
//
// Pipeline:
//   prep:       wcomb bf16 [384][256] = [w_down ; w_out] ; wrb bf16 [112][1152]
//   dual_gemm:  x -> t1T bf16 [n*4096][128] (+b_down) ; xoT bf16 [n*4096][256]
//               (32-pixel tiles, 512 blocks, 2 blocks/CU)
//   conv_sm:    conv3x3(t1, MFMA) + b_enc -> softmax(25) -> SMg f32 [n][tile][25][64][4]
//   reassembly: sm (coalesced) + xo halo -> weighted sum + b_out + pixel-shuffle -> z
//               (1024 blocks, 2 blocks/CU)
//
// MFMA v_mfma_f32_16x16x32_bf16 layout (guide §3, m89-verified):
//   A-frag: row = lane&15, k = (lane>>4)*8 + j
//   B-frag: col = lane&15, k = (lane>>4)*8 + j
//   C/D:    col = lane&15, row = (lane>>4)*4 + r
// Conv C-frag -> softmax mapping: co = 16*mf + 4*l4 + r = 4k+p  =>  k = 4*mf+l4, p = r.

#define NB    4
#define NPIX  4096

typedef short s16x8 __attribute__((ext_vector_type(8)));
typedef float f32x4 __attribute__((ext_vector_type(4)));

#define MFMA16(a, b, c) __builtin_amdgcn_mfma_f32_16x16x32_bf16((a), (b), (c), 0, 0, 0)

__device__ __forceinline__ ushort f2b(float f) {
    __hip_bfloat16 h = __float2bfloat16(f);
    return *(ushort*)&h;
}
__device__ __forceinline__ float b2f(ushort u) {
    unsigned v = ((unsigned)u) << 16;
    return *(float*)&v;
}

// ---------------------------------------------------------------------------
// prep: weight casts/reorders. 227,328 elements, grid 888 x 256.
// ---------------------------------------------------------------------------
__global__ __launch_bounds__(256) void prep_kernel(
    const float* __restrict__ wd, const float* __restrict__ wo,
    const float* __restrict__ we,
    ushort* __restrict__ wcomb, ushort* __restrict__ wrb)
{
    int idx = blockIdx.x * 256 + threadIdx.x;
    if (idx < 98304) {
        float v = (idx < 32768) ? wd[idx] : wo[idx - 32768];
        wcomb[idx] = f2b(v);
    } else if (idx < 227328) {
        int i = idx - 98304;
        int co = i / 1152, k = i - co * 1152;
        int tap = k >> 7, c = k & 127;
        float v = (co < 100) ? we[(co * 128 + c) * 9 + tap] : 0.0f;
        wrb[i] = f2b(v);
    }
}

// ---------------------------------------------------------------------------
// dual_gemm: Out[pix][0..127] = t1T (+b_down) ; [128..383] = xoT.
// Grid (128, NB) = 512 blocks x 256 threads. 32-pixel tile, 17 KB LDS.
// Waves: wp = wid&1 (16-px group), wc = wid>>1 (192-ch half).
// ---------------------------------------------------------------------------
__global__ __launch_bounds__(256, 2) void dual_gemm_kernel(
    const float*  __restrict__ X,      // [NB][256][4096]
    const ushort* __restrict__ Wcomb,  // [384][256]
    const float*  __restrict__ b_down, // [128]
    ushort* __restrict__ T1t,          // [NB*4096][128]
    ushort* __restrict__ XOt)          // [NB*4096][256]
{
    __shared__ __attribute__((aligned(16))) ushort xs[32][264];
    const int n = blockIdx.y, p0 = blockIdx.x * 32;
    const int tid = threadIdx.x, lane = tid & 63, wid = tid >> 6;
    const int l15 = lane & 15, l4 = lane >> 4;

    // stage + transpose-cast: thread tid = channel, 32 pixels
    {
        const float* src = X + (size_t)n * 256 * NPIX + (size_t)tid * NPIX + p0;
        #pragma unroll
        for (int j = 0; j < 8; j++) {
            float4 v = *(const float4*)&src[j * 4];
            xs[j * 4 + 0][tid] = f2b(v.x);
            xs[j * 4 + 1][tid] = f2b(v.y);
            xs[j * 4 + 2][tid] = f2b(v.z);
            xs[j * 4 + 3][tid] = f2b(v.w);
        }
    }
    __syncthreads();

    const int wp = wid & 1;
    const int wc = wid >> 1;
    const int crow = wc * 192;

    f32x4 acc[12] = {};
    #pragma unroll 2
    for (int ks = 0; ks < 8; ks++) {
        int k0 = ks * 32 + l4 * 8;
        s16x8 a = *(const s16x8*)&xs[wp * 16 + l15][k0];
        #pragma unroll
        for (int cf = 0; cf < 12; cf++) {
            s16x8 b = *(const s16x8*)&Wcomb[(size_t)(crow + cf * 16 + l15) * 256 + k0];
            acc[cf] = MFMA16(a, b, acc[cf]);
        }
    }

    #pragma unroll
    for (int cf = 0; cf < 12; cf++) {
        int cbase = crow + cf * 16;       // wave-uniform
        int c = cbase + l15;
        if (cbase < 128) {
            float bb = b_down[c];
            #pragma unroll
            for (int r = 0; r < 4; r++) {
                int pix = p0 + wp * 16 + l4 * 4 + r;
                T1t[(size_t)(n * NPIX + pix) * 128 + c] = f2b(acc[cf][r] + bb);
            }
        } else {
            int c2 = c - 128;
            #pragma unroll
            for (int r = 0; r < 4; r++) {
                int pix = p0 + wp * 16 + l4 * 4 + r;
                XOt[(size_t)(n * NPIX + pix) * 256 + c2] = f2b(acc[cf][r]);
            }
        }
    }
}

// ---------------------------------------------------------------------------
// conv_sm: conv3x3(t1, MFMA) + b_enc -> softmax(25) -> SMg.
// Grid (64, NB) x 256 threads. LDS 53 KB -> up to 3 blocks/CU.
// SMg layout: [n][tile][k(25)][pix(64)][p(4)] f32.
// ---------------------------------------------------------------------------
__global__ __launch_bounds__(256, 3) void conv_sm_kernel(
    const ushort* __restrict__ T1t,  // [NB*4096][128]
    const ushort* __restrict__ Wr,   // [112][1152]
    const float*  __restrict__ Benc, // [100]
    float* __restrict__ SMg)         // [NB][64][25][64][4]
{
    __shared__ __attribute__((aligned(16))) ushort hs[100][136];  // 27.2 KB
    __shared__ float eld[64][101];                                // 25.9 KB

    const int n = blockIdx.y, tile = blockIdx.x;
    const int h0 = (tile >> 3) * 8, w0 = (tile & 7) * 8;
    const int tid = threadIdx.x, lane = tid & 63, wid = tid >> 6;
    const int l15 = lane & 15, l4 = lane >> 4;

    // stage t1 halo (10x10 pixels x 128 ch bf16)
    for (int u = tid; u < 1600; u += 256) {
        int hp = u >> 4, ch = u & 15;
        int r = hp / 10, s = hp - r * 10;
        int gh = h0 - 1 + r, gw = w0 - 1 + s;
        s16x8 v = {};
        if ((unsigned)gh < 64u && (unsigned)gw < 64u)
            v = *(const s16x8*)&T1t[((size_t)n * NPIX + gh * 64 + gw) * 128 + ch * 8];
        *(s16x8*)&hs[hp][ch * 8] = v;
    }
    __syncthreads();

    // conv via MFMA: wave wid owns pixels wid*16..wid*16+15
    {
        const int pl = wid * 16 + l15;
        const int ph = pl >> 3, pw = pl & 7;
        f32x4 acc[7] = {};
        for (int tap = 0; tap < 9; tap++) {
            int dy = tap / 3, dx = tap - dy * 3;
            int hp = (ph + dy) * 10 + pw + dx;
            const ushort* hrow = &hs[hp][l4 * 8];
            const ushort* wrow = &Wr[(size_t)l15 * 1152 + tap * 128 + l4 * 8];
            #pragma unroll
            for (int cb = 0; cb < 4; cb++) {
                s16x8 b = *(const s16x8*)&hrow[cb * 32];
                #pragma unroll
                for (int mf = 0; mf < 7; mf++) {
                    s16x8 a = *(const s16x8*)&wrow[(size_t)mf * 16 * 1152 + cb * 32];
                    acc[mf] = MFMA16(a, b, acc[mf]);
                }
            }
        }
        #pragma unroll
        for (int mf = 0; mf < 7; mf++) {
            #pragma unroll
            for (int r = 0; r < 4; r++) {
                int co = mf * 16 + l4 * 4 + r;
                if (co < 100) eld[pl][co] = acc[mf][r] + Benc[co];
            }
        }
    }
    __syncthreads();

    // softmax over 25 taps per (pixel, sub-pixel p); coalesced global write
    {
        int p = tid & 3, pix = tid >> 2;
        float v[25];
        float mx = -1e30f;
        #pragma unroll
        for (int k = 0; k < 25; k++) { v[k] = eld[pix][4 * k + p]; mx = fmaxf(mx, v[k]); }
        float ssum = 0.0f;
        #pragma unroll
        for (int k = 0; k < 25; k++) { v[k] = __expf(v[k] - mx); ssum += v[k]; }
        float inv = 1.0f / ssum;
        float* dst = SMg + (size_t)(n * 64 + tile) * 6400;
        #pragma unroll
        for (int k = 0; k < 25; k++)
            dst[k * 256 + tid] = v[k] * inv;
    }
}

// ---------------------------------------------------------------------------
// reassembly: sm + xo-halo -> z. Grid (64, 4, NB) = 1024 blocks x 256 threads.
// LDS 63 KB -> 2 blocks/CU.
// ---------------------------------------------------------------------------
__global__ __launch_bounds__(256, 2) void reassembly_kernel(
    const float*  __restrict__ SMg,  // [NB][64][25][64][4]
    const ushort* __restrict__ XOt,  // [NB*4096][256]
    const float*  __restrict__ Bout, // [256]
    float* __restrict__ Z)           // [NB][256][128][128]
{
    __shared__ __attribute__((aligned(16))) float sml[6400];  // 25.6 KB
    __shared__ float xs[64][145];                             // 37.1 KB

    const int tile = blockIdx.x, oc = blockIdx.y, n = blockIdx.z;
    const int h0 = (tile >> 3) * 8, w0 = (tile & 7) * 8;
    const int tid = threadIdx.x;

    // load softmax block (coalesced)
    {
        const float* src = SMg + (size_t)(n * 64 + tile) * 6400;
        #pragma unroll
        for (int j = 0; j < 25; j++)
            sml[j * 256 + tid] = src[j * 256 + tid];
    }

    // stage 12x12 halo x 64 ch of xo (bf16 -> fp32, transposed)
    for (int u = tid; u < 2304; u += 256) {   // 144 px x 16 groups of 4 ch
        int hp = u >> 4, cg = u & 15;
        int r = hp / 12, s = hp - r * 12;
        int gh = h0 - 2 + r, gw = w0 - 2 + s;
        float v0 = 0.f, v1 = 0.f, v2 = 0.f, v3 = 0.f;
        if ((unsigned)gh < 64u && (unsigned)gw < 64u) {
            ushort4 raw = *(const ushort4*)&XOt[((size_t)n * NPIX + gh * 64 + gw) * 256 + oc * 64 + cg * 4];
            v0 = b2f(raw.x); v1 = b2f(raw.y); v2 = b2f(raw.z); v3 = b2f(raw.w);
        }
        xs[cg * 4 + 0][hp] = v0;
        xs[cg * 4 + 1][hp] = v1;
        xs[cg * 4 + 2][hp] = v2;
        xs[cg * 4 + 3][hp] = v3;
    }
    __syncthreads();

    const int pix = tid & 63;
    const int og = tid >> 6;
    const int ph = pix >> 3, pw = pix & 7;

    float acc[16][4] = {};
    for (int k = 0; k < 25; k++) {
        int di = k / 5, dj = k - di * 5;
        float4 wv = *(const float4*)&sml[k * 256 + pix * 4];
        int base = (ph + di) * 12 + pw + dj;
        #pragma unroll
        for (int i = 0; i < 16; i++) {
            float xv = xs[og * 16 + i][base];
            acc[i][0] += xv * wv.x;
            acc[i][1] += xv * wv.y;
            acc[i][2] += xv * wv.z;
            acc[i][3] += xv * wv.w;
        }
    }

    const int gh = h0 + ph, gw = w0 + pw;
    #pragma unroll
    for (int i = 0; i < 16; i++) {
        int o = oc * 64 + og * 16 + i;
        float bb = Bout[o];
        float2 r0 = make_float2(acc[i][0] + bb, acc[i][1] + bb);
        float2 r1 = make_float2(acc[i][2] + bb, acc[i][3] + bb);
        size_t zb = (((size_t)n * 256 + o) * 128 + 2 * gh) * 128 + 2 * gw;
        *(float2*)&Z[zb]       = r0;
        *(float2*)&Z[zb + 128] = r1;
    }
}

// ---------------------------------------------------------------------------
extern "C" void kernel_launch(void* const* d_in, const int* in_sizes, int n_in,
                              void* d_out, int out_size, void* d_ws, size_t ws_size,
                              hipStream_t stream) {
    const float* x      = (const float*)d_in[0];
    const float* w_down = (const float*)d_in[1];
    const float* b_down = (const float*)d_in[2];
    const float* w_enc  = (const float*)d_in[3];
    const float* b_enc  = (const float*)d_in[4];
    const float* w_out  = (const float*)d_in[5];
    const float* b_out  = (const float*)d_in[6];
    float* z = (float*)d_out;

    // workspace layout
    ushort* t1T   = (ushort*)d_ws;        // 4*4096*128 = 2,097,152 ushorts
    ushort* xoT   = t1T + 2097152;        // 4*4096*256 = 4,194,304
    ushort* wcomb = xoT + 4194304;        // 384*256    =    98,304
    ushort* wrb   = wcomb + 98304;        // 112*1152   =   129,024
    float*  smg   = (float*)(wrb + 129024); // 4*64*6400 = 1,638,400 floats

    prep_kernel<<<888, 256, 0, stream>>>(w_down, w_out, w_enc, wcomb, wrb);
    dual_gemm_kernel<<<dim3(128, NB), 256, 0, stream>>>(x, wcomb, b_down, t1T, xoT);
    conv_sm_kernel<<<dim3(64, NB), 256, 0, stream>>>(t1T, wrb, b_enc, smg);
    reassembly_kernel<<<dim3(64, 4, NB), 256, 0, stream>>>(smg, xoT, b_out, z);
}

// Round 6
// 174.205 us; speedup vs baseline: 1.0099x; 1.0099x over previous
//
#include <hip/hip_runtime.h>
#include <hip/hip_bf16.h>

// CARAFE pipeline, 4 kernels, coalescing-fixed.
// x: (4, 256, 64, 64) fp32
// w_down: (128, 256) ; b_down: (128)
// w_enc: (100, 128, 3, 3) ; b_enc: (100)
// w_out: (256, 256) ; b_out: (256)
// out z: (4, 256, 128, 128) fp32
//
// Pipeline:
//   prep:       wcomb bf16 [384][256] = [w_down ; w_out] ; wrb bf16 [112][1152]
//   dual_gemm:  x -> t1T bf16 [n*4096][128] (+b_down) ; xoT bf16 [n*4096][256]
//               (32-pixel tiles, 512 blocks, 2 blocks/CU, coalesced x reads)
//   conv_sm:    conv3x3(t1, MFMA) + b_enc -> softmax(25) -> SMg f32 [n][tile][25][64][4]
//   reassembly: sm + xo halo -> weighted sum + b_out + pixel-shuffle -> z
//               (full-cache-line float4 Z writes)
//
// MFMA v_mfma_f32_16x16x32_bf16 layout (guide §3, m89-verified):
//   A-frag: row = lane&15, k = (lane>>4)*8 + j
//   B-frag: col = lane&15, k = (lane>>4)*8 + j
//   C/D:    col = lane&15, row = (lane>>4)*4 + r
// Conv C-frag -> softmax mapping: co = 16*mf + 4*l4 + r = 4k+p  =>  k = 4*mf+l4, p = r.

#define NB    4
#define NPIX  4096

typedef short s16x8 __attribute__((ext_vector_type(8)));
typedef float f32x4 __attribute__((ext_vector_type(4)));

#define MFMA16(a, b, c) __builtin_amdgcn_mfma_f32_16x16x32_bf16((a), (b), (c), 0, 0, 0)

__device__ __forceinline__ ushort f2b(float f) {
    __hip_bfloat16 h = __float2bfloat16(f);
    return *(ushort*)&h;
}
__device__ __forceinline__ float b2f(ushort u) {
    unsigned v = ((unsigned)u) << 16;
    return *(float*)&v;
}

// ---------------------------------------------------------------------------
// prep: weight casts/reorders. 227,328 elements, grid 888 x 256.
// ---------------------------------------------------------------------------
__global__ __launch_bounds__(256) void prep_kernel(
    const float* __restrict__ wd, const float* __restrict__ wo,
    const float* __restrict__ we,
    ushort* __restrict__ wcomb, ushort* __restrict__ wrb)
{
    int idx = blockIdx.x * 256 + threadIdx.x;
    if (idx < 98304) {
        float v = (idx < 32768) ? wd[idx] : wo[idx - 32768];
        wcomb[idx] = f2b(v);
    } else if (idx < 227328) {
        int i = idx - 98304;
        int co = i / 1152, k = i - co * 1152;
        int tap = k >> 7, c = k & 127;
        float v = (co < 100) ? we[(co * 128 + c) * 9 + tap] : 0.0f;
        wrb[i] = f2b(v);
    }
}

// ---------------------------------------------------------------------------
// dual_gemm: Out[pix][0..127] = t1T (+b_down) ; [128..383] = xoT.
// Grid (128, NB) = 512 blocks x 256 threads. 32-pixel tile, 17 KB LDS.
// x staged with lane-coalesced reads: thread = (pix-quad tid&7, ch-pair tid>>3).
// ---------------------------------------------------------------------------
__global__ __launch_bounds__(256, 2) void dual_gemm_kernel(
    const float*  __restrict__ X,      // [NB][256][4096]
    const ushort* __restrict__ Wcomb,  // [384][256]
    const float*  __restrict__ b_down, // [128]
    ushort* __restrict__ T1t,          // [NB*4096][128]
    ushort* __restrict__ XOt)          // [NB*4096][256]
{
    __shared__ __attribute__((aligned(16))) ushort xs[32][264];
    const int n = blockIdx.y, p0 = blockIdx.x * 32;
    const int tid = threadIdx.x, lane = tid & 63, wid = tid >> 6;
    const int l15 = lane & 15, l4 = lane >> 4;

    // stage + transpose-cast, coalesced: per pass, lanes 8k..8k+7 read 128B
    // contiguous of one channel row. 4 passes x 64 channels.
    {
        const int pix4  = tid & 7;       // which 4-pixel group
        const int cpair = tid >> 3;      // 0..31 channel-pairs per pass
        const float* base = X + (size_t)n * 256 * NPIX + p0 + pix4 * 4;
        #pragma unroll
        for (int pp = 0; pp < 4; pp++) {
            int c = pp * 64 + cpair * 2;
            float4 va = *(const float4*)&base[(size_t)c * NPIX];
            float4 vb = *(const float4*)&base[(size_t)(c + 1) * NPIX];
            float va_[4] = {va.x, va.y, va.z, va.w};
            float vb_[4] = {vb.x, vb.y, vb.z, vb.w};
            #pragma unroll
            for (int j = 0; j < 4; j++) {
                ushort2 w;
                w.x = f2b(va_[j]);
                w.y = f2b(vb_[j]);
                *(ushort2*)&xs[pix4 * 4 + j][c] = w;
            }
        }
    }
    __syncthreads();

    const int wp = wid & 1;         // 16-pixel group
    const int wc = wid >> 1;        // 192-channel half
    const int crow = wc * 192;

    f32x4 acc[12] = {};
    #pragma unroll 2
    for (int ks = 0; ks < 8; ks++) {
        int k0 = ks * 32 + l4 * 8;
        s16x8 a = *(const s16x8*)&xs[wp * 16 + l15][k0];
        #pragma unroll
        for (int cf = 0; cf < 12; cf++) {
            s16x8 b = *(const s16x8*)&Wcomb[(size_t)(crow + cf * 16 + l15) * 256 + k0];
            acc[cf] = MFMA16(a, b, acc[cf]);
        }
    }

    #pragma unroll
    for (int cf = 0; cf < 12; cf++) {
        int cbase = crow + cf * 16;       // wave-uniform
        int c = cbase + l15;
        if (cbase < 128) {
            float bb = b_down[c];
            #pragma unroll
            for (int r = 0; r < 4; r++) {
                int pix = p0 + wp * 16 + l4 * 4 + r;
                T1t[(size_t)(n * NPIX + pix) * 128 + c] = f2b(acc[cf][r] + bb);
            }
        } else {
            int c2 = c - 128;
            #pragma unroll
            for (int r = 0; r < 4; r++) {
                int pix = p0 + wp * 16 + l4 * 4 + r;
                XOt[(size_t)(n * NPIX + pix) * 256 + c2] = f2b(acc[cf][r]);
            }
        }
    }
}

// ---------------------------------------------------------------------------
// conv_sm: conv3x3(t1, MFMA) + b_enc -> softmax(25) -> SMg.
// Grid (64, NB) x 256 threads. LDS 53 KB.
// SMg layout: [n][tile][k(25)][pix(64)][p(4)] f32.
// ---------------------------------------------------------------------------
__global__ __launch_bounds__(256, 3) void conv_sm_kernel(
    const ushort* __restrict__ T1t,  // [NB*4096][128]
    const ushort* __restrict__ Wr,   // [112][1152]
    const float*  __restrict__ Benc, // [100]
    float* __restrict__ SMg)         // [NB][64][25][64][4]
{
    __shared__ __attribute__((aligned(16))) ushort hs[100][136];  // 27.2 KB
    __shared__ float eld[64][101];                                // 25.9 KB

    const int n = blockIdx.y, tile = blockIdx.x;
    const int h0 = (tile >> 3) * 8, w0 = (tile & 7) * 8;
    const int tid = threadIdx.x, lane = tid & 63, wid = tid >> 6;
    const int l15 = lane & 15, l4 = lane >> 4;

    // stage t1 halo (10x10 pixels x 128 ch bf16)
    for (int u = tid; u < 1600; u += 256) {
        int hp = u >> 4, ch = u & 15;
        int r = hp / 10, s = hp - r * 10;
        int gh = h0 - 1 + r, gw = w0 - 1 + s;
        s16x8 v = {};
        if ((unsigned)gh < 64u && (unsigned)gw < 64u)
            v = *(const s16x8*)&T1t[((size_t)n * NPIX + gh * 64 + gw) * 128 + ch * 8];
        *(s16x8*)&hs[hp][ch * 8] = v;
    }
    __syncthreads();

    // conv via MFMA: wave wid owns pixels wid*16..wid*16+15
    {
        const int pl = wid * 16 + l15;
        const int ph = pl >> 3, pw = pl & 7;
        f32x4 acc[7] = {};
        for (int tap = 0; tap < 9; tap++) {
            int dy = tap / 3, dx = tap - dy * 3;
            int hp = (ph + dy) * 10 + pw + dx;
            const ushort* hrow = &hs[hp][l4 * 8];
            const ushort* wrow = &Wr[(size_t)l15 * 1152 + tap * 128 + l4 * 8];
            #pragma unroll
            for (int cb = 0; cb < 4; cb++) {
                s16x8 b = *(const s16x8*)&hrow[cb * 32];
                #pragma unroll
                for (int mf = 0; mf < 7; mf++) {
                    s16x8 a = *(const s16x8*)&wrow[(size_t)mf * 16 * 1152 + cb * 32];
                    acc[mf] = MFMA16(a, b, acc[mf]);
                }
            }
        }
        #pragma unroll
        for (int mf = 0; mf < 7; mf++) {
            #pragma unroll
            for (int r = 0; r < 4; r++) {
                int co = mf * 16 + l4 * 4 + r;
                if (co < 100) eld[pl][co] = acc[mf][r] + Benc[co];
            }
        }
    }
    __syncthreads();

    // softmax over 25 taps per (pixel, sub-pixel p); coalesced global write
    {
        int p = tid & 3, pix = tid >> 2;
        float v[25];
        float mx = -1e30f;
        #pragma unroll
        for (int k = 0; k < 25; k++) { v[k] = eld[pix][4 * k + p]; mx = fmaxf(mx, v[k]); }
        float ssum = 0.0f;
        #pragma unroll
        for (int k = 0; k < 25; k++) { v[k] = __expf(v[k] - mx); ssum += v[k]; }
        float inv = 1.0f / ssum;
        float* dst = SMg + (size_t)(n * 64 + tile) * 6400;
        #pragma unroll
        for (int k = 0; k < 25; k++)
            dst[k * 256 + tid] = v[k] * inv;
    }
}

// ---------------------------------------------------------------------------
// reassembly: sm + xo-halo -> z. Grid (64, 4, NB) = 1024 blocks x 256 threads.
// Thread = (pw-pair tid&3, ph (tid>>2)&7, 8-ch group tid>>5).
// Z stores are float4 with lanes forming full 64B segments.
// ---------------------------------------------------------------------------
__global__ __launch_bounds__(256, 2) void reassembly_kernel(
    const float*  __restrict__ SMg,  // [NB][64][25][64][4]
    const ushort* __restrict__ XOt,  // [NB*4096][256]
    const float*  __restrict__ Bout, // [256]
    float* __restrict__ Z)           // [NB][256][128][128]
{
    __shared__ __attribute__((aligned(16))) float sml[64][100];  // [pix][4k+p], 25.6 KB
    __shared__ float xs[64][145];                                // 37.1 KB

    const int tile = blockIdx.x, oc = blockIdx.y, n = blockIdx.z;
    const int h0 = (tile >> 3) * 8, w0 = (tile & 7) * 8;
    const int tid = threadIdx.x;

    // load softmax block (coalesced read, transposed store)
    {
        const float* src = SMg + (size_t)(n * 64 + tile) * 6400;
        int pix = tid >> 2, p = tid & 3;
        #pragma unroll
        for (int j = 0; j < 25; j++)
            sml[pix][j * 4 + p] = src[j * 256 + tid];
    }

    // stage 12x12 halo x 64 ch of xo (bf16 -> fp32, transposed)
    for (int u = tid; u < 2304; u += 256) {   // 144 px x 16 groups of 4 ch
        int hp = u >> 4, cg = u & 15;
        int r = hp / 12, s = hp - r * 12;
        int gh = h0 - 2 + r, gw = w0 - 2 + s;
        float v0 = 0.f, v1 = 0.f, v2 = 0.f, v3 = 0.f;
        if ((unsigned)gh < 64u && (unsigned)gw < 64u) {
            ushort4 raw = *(const ushort4*)&XOt[((size_t)n * NPIX + gh * 64 + gw) * 256 + oc * 64 + cg * 4];
            v0 = b2f(raw.x); v1 = b2f(raw.y); v2 = b2f(raw.z); v3 = b2f(raw.w);
        }
        xs[cg * 4 + 0][hp] = v0;
        xs[cg * 4 + 1][hp] = v1;
        xs[cg * 4 + 2][hp] = v2;
        xs[cg * 4 + 3][hp] = v3;
    }
    __syncthreads();

    const int pw2 = tid & 3;           // pair of pw: pw = 2*pw2, 2*pw2+1
    const int ph  = (tid >> 2) & 7;
    const int og  = tid >> 5;          // 8-channel group
    const int pix0 = ph * 8 + pw2 * 2;

    float acc[8][8] = {};   // [ch][px*4 + p]
    for (int k = 0; k < 25; k++) {
        int di = k / 5, dj = k - di * 5;
        float4 wv0 = *(const float4*)&sml[pix0][k * 4];
        float4 wv1 = *(const float4*)&sml[pix0 + 1][k * 4];
        int base = (ph + di) * 12 + pw2 * 2 + dj;
        #pragma unroll
        for (int i = 0; i < 8; i++) {
            float xv0 = xs[og * 8 + i][base];
            float xv1 = xs[og * 8 + i][base + 1];
            acc[i][0] += xv0 * wv0.x;
            acc[i][1] += xv0 * wv0.y;
            acc[i][2] += xv0 * wv0.z;
            acc[i][3] += xv0 * wv0.w;
            acc[i][4] += xv1 * wv1.x;
            acc[i][5] += xv1 * wv1.y;
            acc[i][6] += xv1 * wv1.z;
            acc[i][7] += xv1 * wv1.w;
        }
    }

    const int gh = h0 + ph;
    #pragma unroll
    for (int i = 0; i < 8; i++) {
        int o = oc * 64 + og * 8 + i;
        float bb = Bout[o];
        // row 2gh+0: (px0,b0),(px0,b1),(px1,b0),(px1,b1) ; p = a*2+b
        float4 v0 = make_float4(acc[i][0] + bb, acc[i][1] + bb, acc[i][4] + bb, acc[i][5] + bb);
        float4 v1 = make_float4(acc[i][2] + bb, acc[i][3] + bb, acc[i][6] + bb, acc[i][7] + bb);
        size_t zb = (((size_t)n * 256 + o) * 128 + 2 * gh) * 128 + 2 * w0 + 4 * pw2;
        *(float4*)&Z[zb]       = v0;
        *(float4*)&Z[zb + 128] = v1;
    }
}

// ---------------------------------------------------------------------------
extern "C" void kernel_launch(void* const* d_in, const int* in_sizes, int n_in,
                              void* d_out, int out_size, void* d_ws, size_t ws_size,
                              hipStream_t stream) {
    const float* x      = (const float*)d_in[0];
    const float* w_down = (const float*)d_in[1];
    const float* b_down = (const float*)d_in[2];
    const float* w_enc  = (const float*)d_in[3];
    const float* b_enc  = (const float*)d_in[4];
    const float* w_out  = (const float*)d_in[5];
    const float* b_out  = (const float*)d_in[6];
    float* z = (float*)d_out;

    // workspace layout
    ushort* t1T   = (ushort*)d_ws;          // 4*4096*128 = 2,097,152 ushorts
    ushort* xoT   = t1T + 2097152;          // 4*4096*256 = 4,194,304
    ushort* wcomb = xoT + 4194304;          // 384*256    =    98,304
    ushort* wrb   = wcomb + 98304;          // 112*1152   =   129,024
    float*  smg   = (float*)(wrb + 129024); // 4*64*6400  = 1,638,400 floats

    prep_kernel<<<888, 256, 0, stream>>>(w_down, w_out, w_enc, wcomb, wrb);
    dual_gemm_kernel<<<dim3(128, NB), 256, 0, stream>>>(x, wcomb, b_down, t1T, xoT);
    conv_sm_kernel<<<dim3(64, NB), 256, 0, stream>>>(t1T, wrb, b_enc, smg);
    reassembly_kernel<<<dim3(64, 4, NB), 256, 0, stream>>>(smg, xoT, b_out, z);
}